// Round 18
// baseline (183.485 us; speedup 1.0000x reference)
//
#include <hip/hip_runtime.h>
#include <math.h>

// ---------------- problem constants (static shapes) ----------------
#define NIMG 8
#define ATOT 65472
#define KTOT 6960          // 2000+2000+2000+768+192
#define POST 2000
#define TILES_PER_IMG 1668 // 528*3 + 78 + 6
#define NTILES (NIMG*TILES_PER_IMG)
#define ESEG 1024          // edges per (task,gi) segment cap
// Exact tie boundary: f32_div(inter,uni) > 0.7f  <=>  inter/uni >= M_TIE.
// M_TIE = midpoint(0.7f, nextafterf(0.7f)) = 23488103/2^25; ties-to-even sends
// the midpoint UP. (double)inter >= M_TIE*(double)uni is exact: 25b+24b <= 53b.
// Validated bit-exact vs division predicate in rounds 4-14 (absmax 0.0).
#define M_TIE 0.7000000178813934326171875
// LDS padding for the u64 bitonic: +1 slot per 32 elements
#define PAD(i) ((i) + ((i) >> 5))
// wave-local LDS ordering (one-wave NMS: no cross-wave state => no s_barrier)
#define WAVE_SYNC() asm volatile("s_waitcnt lgkmcnt(0)" ::: "memory")

__constant__ int c_NAPL[5]  = {49152,12288,3072,768,192};
__constant__ int c_LOFF[5]  = {0,49152,61440,64512,65280};
__constant__ int c_KSEL[5]  = {2000,2000,2000,768,192};
__constant__ int c_CBASE[5] = {0,2000,4000,6000,6768};
__constant__ int c_GLVL[5]  = {32,32,32,12,3};      // ceil(k/64)
__constant__ int c_TILEPFX[6] = {0,528,1056,1584,1662,1668};

typedef float v2f __attribute__((ext_vector_type(2)));

__device__ __forceinline__ v2f vmin2(v2f a, v2f b){
#if __has_builtin(__builtin_elementwise_min)
  return __builtin_elementwise_min(a, b);
#else
  v2f r; r.x = fminf(a.x, b.x); r.y = fminf(a.y, b.y); return r;
#endif
}
__device__ __forceinline__ v2f vmax2(v2f a, v2f b){
#if __has_builtin(__builtin_elementwise_max)
  return __builtin_elementwise_max(a, b);
#else
  v2f r; r.x = fmaxf(a.x, b.x); r.y = fmaxf(a.y, b.y); return r;
#endif
}

// monotone float->uint map (order-preserving for all finite floats)
__device__ __forceinline__ unsigned f2u(float f){
  unsigned b = __float_as_uint(f);
  return (b & 0x80000000u) ? ~b : (b | 0x80000000u);
}
// composite key: (value desc, global idx asc) when sorted descending
__device__ __forceinline__ unsigned long long mkkey(unsigned u, unsigned gidx){
  return ((unsigned long long)u << 32) | (unsigned long long)(0xFFFFFFFFu - gidx);
}
__device__ __forceinline__ unsigned long long shflx64(unsigned long long v, int m){
  int lo = __shfl_xor((int)(unsigned)v, m);
  int hi = __shfl_xor((int)(unsigned)(v >> 32), m);
  return ((unsigned long long)(unsigned)hi << 32) | (unsigned)lo;
}
// one bitonic compare-exchange substage across lanes (R14-validated pattern);
// flag convention identical to the LDS bitonic: desc block iff (elem&size)==0
__device__ __forceinline__ unsigned long long bstep(unsigned long long v, int elem,
                                                    int size, int st){
  unsigned long long p = shflx64(v, st);
  bool lower = (elem & st) == 0;
  bool desc  = (elem & size) == 0;
  bool takeMax = (lower == desc);
  bool gt = v > p;
  return (takeMax == gt) ? v : p;
}
// wave-internal inclusive SUFFIX sum (lane l gets sum over lanes >= l)
__device__ __forceinline__ unsigned wsuffix(unsigned v, int lane){
  #pragma unroll
  for (int off = 1; off < 64; off <<= 1){
    unsigned p = __shfl_down(v, off);
    if (lane + off < 64) v += p;
  }
  return v;
}
// descending array, unique keys: count entries strictly greater than x
__device__ __forceinline__ int cntGreaterDesc(const unsigned long long* base, int len,
                                              unsigned long long x){
  int lo = 0, hi = len;
  while (lo < hi){
    int mid = (lo + hi) >> 1;
    if (base[mid] > x) lo = mid + 1; else hi = mid;
  }
  return lo;
}

// ---------------- K1: fused select; register-blocked bitonic ----------------
// (R29 form: batched append atomic; zero sweep extended to cover mdone[8])
extern "C" __global__ void __launch_bounds__(1024)
k_select(const float* __restrict__ prop, const float* __restrict__ obj,
         unsigned long long* __restrict__ cand, float4* __restrict__ cbox,
         unsigned* __restrict__ zzone, float4* __restrict__ out4, int out_n4){
  __shared__ unsigned long long sb[2112];  // padded sort buffer (16.9 KB)
  __shared__ unsigned hist[4096];          // 16 KB
  __shared__ unsigned h8[256];
  __shared__ unsigned wsum[16];
  __shared__ unsigned s_b12, s_cumAbove, s_t20, s_cnt;
  int task = blockIdx.x, img = task/5, lvl = task%5;
  int n = c_NAPL[lvl], k = c_KSEL[lvl], tid = threadIdx.x;
  int lane = tid & 63, wv = tid >> 6;
  if (task == 0)
    for (int i = tid; i < 1328; i += 1024) zzone[i] = 0u;  // ecnt+ccnt+mdone
  { // d_out zeroing (moved from k_mask in R26; first consumed by merge phase)
    int z = task*1024 + tid;
    if (z < out_n4) out4[z] = make_float4(0.f,0.f,0.f,0.f);
  }

  const float4* o4 = (const float4*)(obj + (size_t)img*ATOT + c_LOFF[lvl]);
  int n4 = n >> 2;                         // all level sizes divisible by 4
  unsigned kk = (unsigned)k;
  unsigned T = 0u;                         // 20-bit threshold; 0 => append all
  if (k < n){
    for (int i = tid; i < 4096; i += 1024) hist[i] = 0u;
    if (tid < 256) h8[tid] = 0u;
    __syncthreads();
    // sweep 1: 12-bit histogram
    for (int i = tid; i < n4; i += 1024){
      float4 v = o4[i];
      atomicAdd(&hist[f2u(v.x) >> 20], 1u);
      atomicAdd(&hist[f2u(v.y) >> 20], 1u);
      atomicAdd(&hist[f2u(v.z) >> 20], 1u);
      atomicAdd(&hist[f2u(v.w) >> 20], 1u);
    }
    __syncthreads();
    // suffix over 4096 bins: per-thread 4 bins + wave shfl suffix + one combine
    unsigned own[4]; unsigned s = 0;
    int b0 = tid*4;
    #pragma unroll
    for (int j = 0; j < 4; ++j){ own[j] = hist[b0+j]; s += own[j]; }
    {
      unsigned suf = wsuffix(s, lane);         // suffix within wave
      unsigned wtot = __shfl(suf, 0);          // wave total
      if (lane == 0) wsum[wv] = wtot;
      __syncthreads();
      unsigned above = 0;
      for (int w2 = wv + 1; w2 < 16; ++w2) above += wsum[w2];
      unsigned suf_incl = suf + above;         // == old scan[tid]
      unsigned sufn = suf_incl - s;            // suffix strictly after own bins
      #pragma unroll
      for (int j = 3; j >= 0; --j){
        unsigned sufj = sufn + own[j];
        if (sufj >= kk && sufn < kk){ s_b12 = (unsigned)(b0 + j); s_cumAbove = sufn; }
        sufn = sufj;
      }
    }
    __syncthreads();
    unsigned b12 = s_b12;
    // sweep 2: 8-bit refinement within the boundary bin (L2-warm re-read)
    for (int i = tid; i < n4; i += 1024){
      float4 v = o4[i];
      unsigned ux = f2u(v.x), uy = f2u(v.y), uz = f2u(v.z), uw = f2u(v.w);
      if ((ux >> 20) == b12) atomicAdd(&h8[(ux >> 12) & 255u], 1u);
      if ((uy >> 20) == b12) atomicAdd(&h8[(uy >> 12) & 255u], 1u);
      if ((uz >> 20) == b12) atomicAdd(&h8[(uz >> 12) & 255u], 1u);
      if ((uw >> 20) == b12) atomicAdd(&h8[(uw >> 12) & 255u], 1u);
    }
    __syncthreads();
    // suffix over 256 bins: waves 0..3 shfl suffix + one combine
    {
      unsigned hval = 0, suf8 = 0;
      if (tid < 256){
        hval = h8[tid];
        suf8 = wsuffix(hval, lane);
        if (lane == 0) wsum[wv] = suf8;        // wave total (suffix at lane 0)
      }
      __syncthreads();
      if (tid < 256){
        unsigned above = 0;
        for (int w2 = wv + 1; w2 < 4; ++w2) above += wsum[w2];
        unsigned suf_incl = suf8 + above;      // == old scan[tid]
        unsigned cum = s_cumAbove;
        unsigned sufj = cum + suf_incl;
        unsigned sufn = cum + (suf_incl - hval);  // == old scan[tid+1] (0 at 255)
        if (sufj >= kk && sufn < kk) s_t20 = (s_b12 << 8) | (unsigned)tid;
      }
    }
    __syncthreads();
    T = s_t20;
  }
  if (tid == 0) s_cnt = 0u;
  __syncthreads();
  // sweep 3: append (u>>12) >= T — R29: one batched LDS atomic per wave-iter
  int abase = c_LOFF[lvl];
  for (int i = tid; i < n4; i += 1024){
    float4 v = o4[i];
    float vv[4] = {v.x, v.y, v.z, v.w};
    unsigned u4[4]; bool pr4[4];
    unsigned long long bm4[4]; unsigned cw4[4];
    unsigned tot = 0;
    #pragma unroll
    for (int c2 = 0; c2 < 4; ++c2){
      u4[c2] = f2u(vv[c2]);
      pr4[c2] = (u4[c2] >> 12) >= T;
      bm4[c2] = __ballot(pr4[c2]);
      cw4[c2] = (unsigned)__popcll(bm4[c2]);
      tot += cw4[c2];
    }
    unsigned basep = 0;
    if (lane == 0 && tot) basep = atomicAdd(&s_cnt, tot);
    basep = __shfl(basep, 0);
    unsigned run = 0;
    #pragma unroll
    for (int c2 = 0; c2 < 4; ++c2){
      if (pr4[c2]){
        unsigned p = basep + run +
                     (unsigned)__popcll(bm4[c2] & ((1ull << lane) - 1ull));
        if (p < 2048u) sb[PAD(p)] = mkkey(u4[c2], (unsigned)(abase + i*4 + c2));
      }
      run += cw4[c2];
    }
  }
  __syncthreads();
  int cnt = (int)min(s_cnt, 2048u);
  int m = 256; while (m < k || m < cnt) m <<= 1;   // 2048 / 1024 / 256
  for (int i = cnt + tid; i < m; i += 1024) sb[PAD(i)] = 0ull;  // 0-key sorts last
  __syncthreads();

  // ---- register-blocked bitonic, descending ----
  int elemA = (wv << 7) | lane, elemB = elemA | 64;
  bool active = (elemA < m);
  unsigned long long va = 0ull, vb = 0ull;
  if (active){ va = sb[PAD(elemA)]; vb = sb[PAD(elemB)]; }
  if (active){
    for (int size = 2; size <= 64; size <<= 1)
      for (int st = size >> 1; st >= 1; st >>= 1){
        va = bstep(va, elemA, size, st);
        vb = bstep(vb, elemB, size, st);
      }
    {
      bool desc = ((elemA & 128) == 0);
      unsigned long long mx = (va > vb) ? va : vb;
      unsigned long long mn = (va > vb) ? vb : va;
      va = desc ? mx : mn; vb = desc ? mn : mx;
      for (int st = 32; st >= 1; st >>= 1){
        va = bstep(va, elemA, 128, st);
        vb = bstep(vb, elemB, 128, st);
      }
    }
  }
  for (int S = 256; S <= m; S <<= 1){
    if (active){ sb[PAD(elemA)] = va; sb[PAD(elemB)] = vb; }
    __syncthreads();
    for (int st = S >> 1; st >= 128; st >>= 1){
      for (int t = tid; t < (m >> 1); t += 1024){
        int lo = t & (st - 1);
        int i  = ((t - lo) << 1) + lo;
        int j  = i + st;
        bool desc = ((i & S) == 0);
        unsigned long long x = sb[PAD(i)], y = sb[PAD(j)];
        if (desc ? (x < y) : (x > y)){ sb[PAD(i)] = y; sb[PAD(j)] = x; }
      }
      __syncthreads();
    }
    if (active){
      va = sb[PAD(elemA)]; vb = sb[PAD(elemB)];
      bool desc = ((elemA & S) == 0);   // elemB has same bit for S >= 256
      unsigned long long mx = (va > vb) ? va : vb;
      unsigned long long mn = (va > vb) ? vb : va;
      va = desc ? mx : mn; vb = desc ? mn : mx;
      for (int st = 32; st >= 1; st >>= 1){
        va = bstep(va, elemA, S, st);
        vb = bstep(vb, elemB, S, st);
      }
    }
  }
  // emit straight from registers: element index == descending rank
  const float4* pr = (const float4*)(prop + (size_t)img*ATOT*4);
  size_t base = (size_t)img*KTOT + c_CBASE[lvl];
  if (active){
    if (elemA < k){
      cand[base + elemA] = va;
      unsigned gidx = 0xFFFFFFFFu - (unsigned)(va & 0xFFFFFFFFull);
      float4 p = pr[gidx];
      cbox[base + elemA] = make_float4(fminf(fmaxf(p.x,0.f),512.f), fminf(fmaxf(p.y,0.f),512.f),
                                       fminf(fmaxf(p.z,0.f),512.f), fminf(fmaxf(p.w,0.f),512.f));
    }
    if (elemB < k){
      cand[base + elemB] = vb;
      unsigned gidx = 0xFFFFFFFFu - (unsigned)(vb & 0xFFFFFFFFull);
      float4 p = pr[gidx];
      cbox[base + elemB] = make_float4(fminf(fmaxf(p.x,0.f),512.f), fminf(fmaxf(p.y,0.f),512.f),
                                       fminf(fmaxf(p.z,0.f),512.f), fminf(fmaxf(p.w,0.f),512.f));
    }
  }
}

// ---------------- K2: IoU tiles -> edge lists (R25 packed form, validated) ----------------
extern "C" __global__ void __launch_bounds__(256)
k_mask(const float4* __restrict__ cbox, unsigned* __restrict__ ecnt,
       unsigned* __restrict__ eseg){
  __shared__ float4 pairXY[4][32];
  __shared__ float4 pairZW[4][32];
  int tid = threadIdx.x, lane = tid & 63, wv = tid >> 6;
  int bid = blockIdx.x;
  int tile = bid*4 + wv;                 // NTILES = 13344 = 3336*4, no remainder
  int img = tile / TILES_PER_IMG, r = tile % TILES_PER_IMG;
  int lvl = 0;
  while (r >= c_TILEPFX[lvl + 1]) ++lvl;
  int t = r - c_TILEPFX[lvl];
  int G = c_GLVL[lvl], k = c_KSEL[lvl];
  int gi = 0;
  while (t >= G - gi){ t -= G - gi; ++gi; }
  int gj = gi + t;
  int task = img*5 + lvl;
  const float4* cb = cbox + (size_t)img*KTOT + c_CBASE[lvl];

  int jj = gj*64 + lane;
  float4 bb = (jj < k) ? cb[jj] : make_float4(0.f,0.f,0.f,0.f);
  // partner box via shfl_xor(1); even lane writes XY quad, odd writes ZW quad
  float px_ = __shfl_xor(bb.x, 1), py_ = __shfl_xor(bb.y, 1);
  float pz_ = __shfl_xor(bb.z, 1), pw_ = __shfl_xor(bb.w, 1);
  int m2 = lane >> 1;
  if ((lane & 1) == 0)
    pairXY[wv][m2] = make_float4(bb.x, px_, bb.y, py_);   // {x_e, x_o, y_e, y_o}
  else
    pairZW[wv][m2] = make_float4(pz_, bb.z, pw_, bb.w);   // {z_e, z_o, w_e, w_o}
  WAVE_SYNC();   // own wave's ds_writes retired; no cross-wave state => no barrier

  int i = gi*64 + lane;
  float4 a = cb[(i < k) ? i : (k - 1)];  // clamped row; masked after the loop
  float aarea = (a.z - a.x) * (a.w - a.y);
  v2f az = {a.z, a.z}, ax = {a.x, a.x}, aw = {a.w, a.w}, ay = {a.y, a.y};
  v2f aA = {aarea, aarea};
  const float4* pxy = pairXY[wv];
  const float4* pzw = pairZW[wv];
  unsigned long long word = 0ull;
  #pragma unroll
  for (int jp = 0; jp < 32; ++jp){
    float4 q1 = pxy[jp];                 // wave-uniform ds_read_b128
    float4 q2 = pzw[jp];                 // wave-uniform ds_read_b128
    v2f bx = {q1.x, q1.y}, by = {q1.z, q1.w};
    v2f bz = {q2.x, q2.y}, bw = {q2.z, q2.w};
    v2f ix = vmin2(az, bz) - vmax2(ax, bx);
    v2f iy = vmin2(aw, bw) - vmax2(ay, by);
    v2f inter = ix * iy;
    v2f bA = (bz - bx) * (bw - by);
    v2f uni = (aA + bA) - inter;
    v2f p7 = uni * 0.7f;
    int d0 = __float_as_int(inter.x) - __float_as_int(p7.x);
    int d1 = __float_as_int(inter.y) - __float_as_int(p7.y);
    bool ov0 = (ix.x > 0.f) & (iy.x > 0.f);
    bool ov1 = (ix.y > 0.f) & (iy.y > 0.f);
    bool hit0 = ov0 & (d0 > 8);
    bool hit1 = ov1 & (d1 > 8);
    bool amb0 = ov0 & ((unsigned)(d0 + 8) <= 16u);   // == (d0>-9)&(d0<=8)
    bool amb1 = ov1 & ((unsigned)(d1 + 8) <= 16u);
    if (__any(amb0 | amb1)){             // wave-uniform s_cbranch; ~never taken
      if (amb0 && ((double)inter.x >= M_TIE * (double)uni.x)) hit0 = true;
      if (amb1 && ((double)inter.y >= M_TIE * (double)uni.y)) hit1 = true;
    }
    word |= (hit0 ? (1ull << (2*jp)) : 0ull) | (hit1 ? (1ull << (2*jp + 1)) : 0ull);
  }
  if (i >= k) word = 0ull;
  if (gi == gj)
    word &= (lane == 63) ? 0ull : (~0ull << (lane + 1));

  int nb = __popcll(word);
  int pfx = nb;
  for (int d = 1; d < 64; d <<= 1){
    int v = __shfl_up(pfx, d);
    if (lane >= d) pfx += v;
  }
  int total = __shfl(pfx, 63);
  if (total > 0){
    unsigned base = 0;
    if (lane == 0) base = atomicAdd(&ecnt[task*32 + gi], (unsigned)total);
    base = __shfl(base, 0);
    unsigned idx = base + (unsigned)(pfx - nb);
    unsigned* ep = eseg + (size_t)(task*32 + gi)*ESEG;
    while (word){
      int j = __ffsll(word) - 1; word &= word - 1;
      if (idx < ESEG) ep[idx] = ((unsigned)i << 16) | (unsigned)(gj*64 + j);
      ++idx;
    }
  }
}

// ---------------- K3: NMS word-sweep + fused per-image merge (R30) ----------------
// Scan phases verbatim (R22, validated). R30: the 5th scan block to finish an
// image runs that image's 5-way rank merge inline. Release: __threadfence()
// then atomicAdd(&mdone[img],1) (device scope); acquire: fence after observing
// old==4. Only 40 fences device-wide (R18's 13K-wave fence cost absent); no
// spinning => no dispatch-order assumption. Merge output deterministic (same
// data regardless of which block triggers). LDS overlays scan's ledge/smA
// with merge's keys (scan state dead after compaction).
extern "C" __global__ void __launch_bounds__(1024)
k_scan(const float* __restrict__ prop, const float* __restrict__ obj,
       const unsigned long long* __restrict__ cand, const unsigned* __restrict__ ecnt,
       const unsigned* __restrict__ eseg, unsigned long long* __restrict__ clist,
       unsigned* __restrict__ ccnt, unsigned* __restrict__ mdone,
       float* __restrict__ out){
  __shared__ unsigned long long ubuf[KTOT];   // 55.7 KB overlay: scan then keys
  unsigned* ledge = (unsigned*)ubuf;          // [6144] u32 (24 KB)
  unsigned long long* smA = ubuf + 3072;      // [32*64] u64 (16 KB) after ledge
  __shared__ unsigned soff[33], wpfx[33];
  __shared__ unsigned long long hasIw[32];
  __shared__ unsigned long long remW[32], keepW[32];
  __shared__ int s_last;
  __shared__ int loff[6], lcnt[5];
  int task = blockIdx.x, img = task / 5, lvl = task % 5;
  int k = c_KSEL[lvl], nW = c_GLVL[lvl], tid = threadIdx.x;
  int lane = tid & 63, wv = tid >> 6;

  // parallel header: concurrent ecnt loads + wave prefix scan (lanes 0..31)
  if (tid < 32){
    unsigned e = (tid < nW) ? min(ecnt[task*32 + tid], (unsigned)ESEG) : 0u;
    unsigned pfx = e;
    #pragma unroll
    for (int d2 = 1; d2 < 32; d2 <<= 1){
      unsigned v = __shfl_up(pfx, d2);
      if (tid >= d2) pfx += v;
    }
    soff[tid] = pfx - e;          // exclusive prefix; lane nW (e=0) writes total
    if (tid == 31) soff[32] = pfx;
    remW[tid] = 0ull; hasIw[tid] = 0ull;
  }
  for (int i = tid; i < 32*64; i += 1024) smA[i] = 0ull;
  __syncthreads();
  // wave-parallel staging + build: wave v handles segments v, v+16
  for (int w = wv; w < nW; w += 16){
    unsigned c = soff[w+1] - soff[w];
    const unsigned* ep = eseg + (size_t)(task*32 + w)*ESEG;
    for (unsigned e = lane; e < c; e += 64){
      unsigned p = soff[w] + e;
      unsigned ed = ep[e];
      if (p < 6144u) ledge[p] = ed;
      int i = (int)(ed >> 16), j = (int)(ed & 0xFFFFu);
      if ((j >> 6) == w){                  // intra-word edge of word w
        atomicOr(&smA[(w << 6) + (i & 63)], 1ull << (j & 63));
        atomicOr(&hasIw[w], 1ull << (i & 63));
      }
    }
  }
  __syncthreads();

  if (tid < 64){     // wave 0: short serial greedy sweep over words
    for (int w = 0; w < nW; ++w){
      unsigned long long smreg = smA[(w << 6) + lane];  // lane holds row `lane`
      unsigned long long r = remW[w];           // includes earlier propagations
      unsigned long long x = hasIw[w] & ~r;
      WAVE_SYNC();                              // smreg valid before readlane
      while (x){
        int i = __ffsll(x) - 1;
        unsigned rlo = __builtin_amdgcn_readlane((unsigned)smreg, i);
        unsigned rhi = __builtin_amdgcn_readlane((unsigned)(smreg >> 32), i);
        unsigned long long row = ((unsigned long long)rhi << 32) | rlo;
        r |= row;
        x &= ~(1ull << i);
        x &= ~r;
      }
      if (lane == 0) remW[w] = r;
      unsigned long long keep_w = ~r;           // all lanes computed r identically
      // propagate to later words using segment-w edges
      unsigned c = soff[w+1] - soff[w];
      if (c){
        const unsigned* ep = eseg + (size_t)(task*32 + w)*ESEG;
        for (unsigned e = lane; e < c; e += 64){
          unsigned p = soff[w] + e;
          unsigned ed = (p < 6144u) ? ledge[p] : ep[e];
          int i = (int)(ed >> 16), j = (int)(ed & 0xFFFFu), wj = j >> 6;
          if (wj != w && ((keep_w >> (i & 63)) & 1ull))
            atomicOr(&remW[wj], 1ull << (j & 63));
        }
      }
      WAVE_SYNC();                              // propagations visible next word
    }
    if (lane < 32){
      unsigned long long v = 0ull;
      if (lane < nW){
        int rem = k - lane*64;
        v = (rem >= 64) ? ~0ull : ((1ull << rem) - 1ull);
      }
      keepW[lane] = v & ~remW[lane];
    }
    WAVE_SYNC();
    if (lane == 0){
      unsigned s = 0;
      for (int w = 0; w < nW; ++w){ wpfx[w] = s; s += (unsigned)__popcll(keepW[w]); }
      ccnt[task] = s;
    }
  }
  __syncthreads();
  // compact kept candidates (preserves sorted order)
  size_t base = (size_t)img*KTOT + c_CBASE[lvl];
  for (int i = tid; i < k; i += 1024){
    unsigned long long w = keepW[i >> 6];
    if ((w >> (i & 63)) & 1ull){
      unsigned long long lowmask = (i & 63) ? ((1ull << (i & 63)) - 1ull) : 0ull;
      unsigned rank = wpfx[i >> 6] + (unsigned)__popcll(w & lowmask);
      clist[base + rank] = cand[base + i];
    }
  }
  __syncthreads();

  // ---- completion counter: last scan block of this image merges it ----
  if (tid == 0){
    __threadfence();                            // release clist/ccnt writes
    unsigned old = atomicAdd(&mdone[img], 1u);  // device-scope
    s_last = (old == 4u) ? 1 : 0;
  }
  __syncthreads();
  if (!s_last) return;
  __threadfence();                              // acquire other tasks' writes

  // ---- merge phase (verbatim k_merge body, full range on one block) ----
  unsigned long long* keys = ubuf;              // overlay reuse
  if (tid < 5) lcnt[tid] = (int)ccnt[img*5 + tid];
  __syncthreads();
  if (tid == 0){
    int s2 = 0;
    for (int l = 0; l < 5; ++l){ loff[l] = s2; s2 += lcnt[l]; }
    loff[5] = s2;
  }
  __syncthreads();
  if (wv < 15){   // wave-parallel staging (R23 pattern)
    int l = wv % 5, sub = wv / 5;
    size_t gb = (size_t)img*KTOT + c_CBASE[l];
    int c = lcnt[l], lo2 = loff[l];
    for (int e = sub*64 + lane; e < c; e += 192) keys[lo2 + e] = clist[gb + e];
  }
  __syncthreads();
  const float4* pr = (const float4*)(prop + (size_t)img*ATOT*4);
  const float*  o  = obj + (size_t)img*ATOT;
  float* ob = out + (size_t)img*POST*4;
  float* os = out + (size_t)NIMG*POST*4 + (size_t)img*POST;
  int tot = loff[5];
  for (int t = tid; t < tot; t += 1024){
    int lv2 = 0;
    while (t >= loff[lv2 + 1]) ++lv2;
    unsigned long long x = keys[t];
    int pos = t - loff[lv2];
    for (int l = 0; l < 5; ++l){
      if (l == lv2) continue;
      pos += cntGreaterDesc(keys + loff[l], lcnt[l], x);
    }
    if (pos < POST){
      unsigned gidx = 0xFFFFFFFFu - (unsigned)(x & 0xFFFFFFFFull);
      float4 p = pr[gidx];
      ob[pos*4 + 0] = fminf(fmaxf(p.x, 0.f), 512.f);
      ob[pos*4 + 1] = fminf(fmaxf(p.y, 0.f), 512.f);
      ob[pos*4 + 2] = fminf(fmaxf(p.z, 0.f), 512.f);
      ob[pos*4 + 3] = fminf(fmaxf(p.w, 0.f), 512.f);
      double sgm = 1.0 / (1.0 + exp(-(double)o[gidx]));  // correctly-rounded f32 sigmoid
      os[pos] = (float)sgm;
    }
  }
}

// ---------------- launch ----------------
extern "C" void kernel_launch(void* const* d_in, const int* in_sizes, int n_in,
                              void* d_out, int out_size, void* d_ws, size_t ws_size,
                              hipStream_t stream){
  const float* prop = (const float*)d_in[0];
  const float* obj  = (const float*)d_in[1];
  char* ws = (char*)d_ws;
  // ws layout (bytes):
  unsigned*           ecnt = (unsigned*)(ws);                        // 40*32*4 = 5120
  unsigned*           ccnt = (unsigned*)(ws + 5120);                 // 160 -> 5280
  unsigned*           mdone= (unsigned*)(ws + 5280);                 // 32 -> 5312 (pad 5632)
  unsigned long long* cand = (unsigned long long*)(ws + 5632);       // 445440 -> 451072
  unsigned long long* clist= (unsigned long long*)(ws + 451072);     // 445440 -> 896512
  float4*             cbox = (float4*)(ws + 896512);                 // 890880 -> 1787392
  unsigned*           eseg = (unsigned*)(ws + 1787392);              // 5242880 -> 7030272

  int out_n4 = out_size / 4;   // 80000 floats = 20000 float4
  hipLaunchKernelGGL(k_select, dim3(40),  dim3(1024), 0, stream, prop, obj, cand, cbox,
                     ecnt, (float4*)d_out, out_n4);
  hipLaunchKernelGGL(k_mask,   dim3(NTILES/4), dim3(256), 0, stream, cbox, ecnt, eseg);
  hipLaunchKernelGGL(k_scan,   dim3(40),  dim3(1024), 0, stream, prop, obj, cand, ecnt,
                     eseg, clist, ccnt, mdone, (float*)d_out);
}

// Round 19
// 160.845 us; speedup vs baseline: 1.1408x; 1.1408x over previous
//
#include <hip/hip_runtime.h>
#include <math.h>

// ---------------- problem constants (static shapes) ----------------
#define NIMG 8
#define ATOT 65472
#define KTOT 6960          // 2000+2000+2000+768+192
#define POST 2000
#define TILES_PER_IMG 1668 // 528*3 + 78 + 6
#define NTILES (NIMG*TILES_PER_IMG)
#define ESEG 1024          // edges per (task,gi) segment cap
// Exact tie boundary: f32_div(inter,uni) > 0.7f  <=>  inter/uni >= M_TIE.
// M_TIE = midpoint(0.7f, nextafterf(0.7f)) = 23488103/2^25; ties-to-even sends
// the midpoint UP. (double)inter >= M_TIE*(double)uni is exact: 25b+24b <= 53b.
// Validated bit-exact vs division predicate in rounds 4-14 (absmax 0.0).
#define M_TIE 0.7000000178813934326171875
// LDS padding for the u64 bitonic: +1 slot per 32 elements
#define PAD(i) ((i) + ((i) >> 5))
// wave-local LDS ordering (one-wave NMS: no cross-wave state => no s_barrier)
#define WAVE_SYNC() asm volatile("s_waitcnt lgkmcnt(0)" ::: "memory")

__constant__ int c_NAPL[5]  = {49152,12288,3072,768,192};
__constant__ int c_LOFF[5]  = {0,49152,61440,64512,65280};
__constant__ int c_KSEL[5]  = {2000,2000,2000,768,192};
__constant__ int c_CBASE[5] = {0,2000,4000,6000,6768};
__constant__ int c_GLVL[5]  = {32,32,32,12,3};      // ceil(k/64)
__constant__ int c_TILEPFX[6] = {0,528,1056,1584,1662,1668};

typedef float v2f __attribute__((ext_vector_type(2)));

__device__ __forceinline__ v2f vmin2(v2f a, v2f b){
#if __has_builtin(__builtin_elementwise_min)
  return __builtin_elementwise_min(a, b);
#else
  v2f r; r.x = fminf(a.x, b.x); r.y = fminf(a.y, b.y); return r;
#endif
}
__device__ __forceinline__ v2f vmax2(v2f a, v2f b){
#if __has_builtin(__builtin_elementwise_max)
  return __builtin_elementwise_max(a, b);
#else
  v2f r; r.x = fmaxf(a.x, b.x); r.y = fmaxf(a.y, b.y); return r;
#endif
}

// monotone float->uint map (order-preserving for all finite floats)
__device__ __forceinline__ unsigned f2u(float f){
  unsigned b = __float_as_uint(f);
  return (b & 0x80000000u) ? ~b : (b | 0x80000000u);
}
// composite key: (value desc, global idx asc) when sorted descending
__device__ __forceinline__ unsigned long long mkkey(unsigned u, unsigned gidx){
  return ((unsigned long long)u << 32) | (unsigned long long)(0xFFFFFFFFu - gidx);
}
__device__ __forceinline__ unsigned long long shflx64(unsigned long long v, int m){
  int lo = __shfl_xor((int)(unsigned)v, m);
  int hi = __shfl_xor((int)(unsigned)(v >> 32), m);
  return ((unsigned long long)(unsigned)hi << 32) | (unsigned)lo;
}
// one bitonic compare-exchange substage across lanes (R14-validated pattern);
// flag convention identical to the LDS bitonic: desc block iff (elem&size)==0
__device__ __forceinline__ unsigned long long bstep(unsigned long long v, int elem,
                                                    int size, int st){
  unsigned long long p = shflx64(v, st);
  bool lower = (elem & st) == 0;
  bool desc  = (elem & size) == 0;
  bool takeMax = (lower == desc);
  bool gt = v > p;
  return (takeMax == gt) ? v : p;
}
// wave-internal inclusive SUFFIX sum (lane l gets sum over lanes >= l)
__device__ __forceinline__ unsigned wsuffix(unsigned v, int lane){
  #pragma unroll
  for (int off = 1; off < 64; off <<= 1){
    unsigned p = __shfl_down(v, off);
    if (lane + off < 64) v += p;
  }
  return v;
}

// ---------------- K1: fused select; register-blocked bitonic ----------------
// (R29 form: batched append atomic — best measured configuration, 161.8us R16)
extern "C" __global__ void __launch_bounds__(1024)
k_select(const float* __restrict__ prop, const float* __restrict__ obj,
         unsigned long long* __restrict__ cand, float4* __restrict__ cbox,
         unsigned* __restrict__ zzone, float4* __restrict__ out4, int out_n4){
  __shared__ unsigned long long sb[2112];  // padded sort buffer (16.9 KB)
  __shared__ unsigned hist[4096];          // 16 KB
  __shared__ unsigned h8[256];
  __shared__ unsigned wsum[16];
  __shared__ unsigned s_b12, s_cumAbove, s_t20, s_cnt;
  int task = blockIdx.x, img = task/5, lvl = task%5;
  int n = c_NAPL[lvl], k = c_KSEL[lvl], tid = threadIdx.x;
  int lane = tid & 63, wv = tid >> 6;
  if (task == 0)
    for (int i = tid; i < 1328; i += 1024) zzone[i] = 0u;  // ecnt+ccnt
  { // d_out zeroing (moved from k_mask in R26; first consumed by k_merge)
    int z = task*1024 + tid;
    if (z < out_n4) out4[z] = make_float4(0.f,0.f,0.f,0.f);
  }

  const float4* o4 = (const float4*)(obj + (size_t)img*ATOT + c_LOFF[lvl]);
  int n4 = n >> 2;                         // all level sizes divisible by 4
  unsigned kk = (unsigned)k;
  unsigned T = 0u;                         // 20-bit threshold; 0 => append all
  if (k < n){
    for (int i = tid; i < 4096; i += 1024) hist[i] = 0u;
    if (tid < 256) h8[tid] = 0u;
    __syncthreads();
    // sweep 1: 12-bit histogram
    for (int i = tid; i < n4; i += 1024){
      float4 v = o4[i];
      atomicAdd(&hist[f2u(v.x) >> 20], 1u);
      atomicAdd(&hist[f2u(v.y) >> 20], 1u);
      atomicAdd(&hist[f2u(v.z) >> 20], 1u);
      atomicAdd(&hist[f2u(v.w) >> 20], 1u);
    }
    __syncthreads();
    // suffix over 4096 bins: per-thread 4 bins + wave shfl suffix + one combine
    unsigned own[4]; unsigned s = 0;
    int b0 = tid*4;
    #pragma unroll
    for (int j = 0; j < 4; ++j){ own[j] = hist[b0+j]; s += own[j]; }
    {
      unsigned suf = wsuffix(s, lane);         // suffix within wave
      unsigned wtot = __shfl(suf, 0);          // wave total
      if (lane == 0) wsum[wv] = wtot;
      __syncthreads();
      unsigned above = 0;
      for (int w2 = wv + 1; w2 < 16; ++w2) above += wsum[w2];
      unsigned suf_incl = suf + above;         // == old scan[tid]
      unsigned sufn = suf_incl - s;            // suffix strictly after own bins
      #pragma unroll
      for (int j = 3; j >= 0; --j){
        unsigned sufj = sufn + own[j];
        if (sufj >= kk && sufn < kk){ s_b12 = (unsigned)(b0 + j); s_cumAbove = sufn; }
        sufn = sufj;
      }
    }
    __syncthreads();
    unsigned b12 = s_b12;
    // sweep 2: 8-bit refinement within the boundary bin (L2-warm re-read)
    for (int i = tid; i < n4; i += 1024){
      float4 v = o4[i];
      unsigned ux = f2u(v.x), uy = f2u(v.y), uz = f2u(v.z), uw = f2u(v.w);
      if ((ux >> 20) == b12) atomicAdd(&h8[(ux >> 12) & 255u], 1u);
      if ((uy >> 20) == b12) atomicAdd(&h8[(uy >> 12) & 255u], 1u);
      if ((uz >> 20) == b12) atomicAdd(&h8[(uz >> 12) & 255u], 1u);
      if ((uw >> 20) == b12) atomicAdd(&h8[(uw >> 12) & 255u], 1u);
    }
    __syncthreads();
    // suffix over 256 bins: waves 0..3 shfl suffix + one combine
    {
      unsigned hval = 0, suf8 = 0;
      if (tid < 256){
        hval = h8[tid];
        suf8 = wsuffix(hval, lane);
        if (lane == 0) wsum[wv] = suf8;        // wave total (suffix at lane 0)
      }
      __syncthreads();
      if (tid < 256){
        unsigned above = 0;
        for (int w2 = wv + 1; w2 < 4; ++w2) above += wsum[w2];
        unsigned suf_incl = suf8 + above;      // == old scan[tid]
        unsigned cum = s_cumAbove;
        unsigned sufj = cum + suf_incl;
        unsigned sufn = cum + (suf_incl - hval);  // == old scan[tid+1] (0 at 255)
        if (sufj >= kk && sufn < kk) s_t20 = (s_b12 << 8) | (unsigned)tid;
      }
    }
    __syncthreads();
    T = s_t20;
  }
  if (tid == 0) s_cnt = 0u;
  __syncthreads();
  // sweep 3: append (u>>12) >= T — R29: one batched LDS atomic per wave-iter
  int abase = c_LOFF[lvl];
  for (int i = tid; i < n4; i += 1024){
    float4 v = o4[i];
    float vv[4] = {v.x, v.y, v.z, v.w};
    unsigned u4[4]; bool pr4[4];
    unsigned long long bm4[4]; unsigned cw4[4];
    unsigned tot = 0;
    #pragma unroll
    for (int c2 = 0; c2 < 4; ++c2){
      u4[c2] = f2u(vv[c2]);
      pr4[c2] = (u4[c2] >> 12) >= T;
      bm4[c2] = __ballot(pr4[c2]);
      cw4[c2] = (unsigned)__popcll(bm4[c2]);
      tot += cw4[c2];
    }
    unsigned basep = 0;
    if (lane == 0 && tot) basep = atomicAdd(&s_cnt, tot);
    basep = __shfl(basep, 0);
    unsigned run = 0;
    #pragma unroll
    for (int c2 = 0; c2 < 4; ++c2){
      if (pr4[c2]){
        unsigned p = basep + run +
                     (unsigned)__popcll(bm4[c2] & ((1ull << lane) - 1ull));
        if (p < 2048u) sb[PAD(p)] = mkkey(u4[c2], (unsigned)(abase + i*4 + c2));
      }
      run += cw4[c2];
    }
  }
  __syncthreads();
  int cnt = (int)min(s_cnt, 2048u);
  int m = 256; while (m < k || m < cnt) m <<= 1;   // 2048 / 1024 / 256
  for (int i = cnt + tid; i < m; i += 1024) sb[PAD(i)] = 0ull;  // 0-key sorts last
  __syncthreads();

  // ---- register-blocked bitonic, descending ----
  int elemA = (wv << 7) | lane, elemB = elemA | 64;
  bool active = (elemA < m);
  unsigned long long va = 0ull, vb = 0ull;
  if (active){ va = sb[PAD(elemA)]; vb = sb[PAD(elemB)]; }
  if (active){
    for (int size = 2; size <= 64; size <<= 1)
      for (int st = size >> 1; st >= 1; st >>= 1){
        va = bstep(va, elemA, size, st);
        vb = bstep(vb, elemB, size, st);
      }
    {
      bool desc = ((elemA & 128) == 0);
      unsigned long long mx = (va > vb) ? va : vb;
      unsigned long long mn = (va > vb) ? vb : va;
      va = desc ? mx : mn; vb = desc ? mn : mx;
      for (int st = 32; st >= 1; st >>= 1){
        va = bstep(va, elemA, 128, st);
        vb = bstep(vb, elemB, 128, st);
      }
    }
  }
  for (int S = 256; S <= m; S <<= 1){
    if (active){ sb[PAD(elemA)] = va; sb[PAD(elemB)] = vb; }
    __syncthreads();
    for (int st = S >> 1; st >= 128; st >>= 1){
      for (int t = tid; t < (m >> 1); t += 1024){
        int lo = t & (st - 1);
        int i  = ((t - lo) << 1) + lo;
        int j  = i + st;
        bool desc = ((i & S) == 0);
        unsigned long long x = sb[PAD(i)], y = sb[PAD(j)];
        if (desc ? (x < y) : (x > y)){ sb[PAD(i)] = y; sb[PAD(j)] = x; }
      }
      __syncthreads();
    }
    if (active){
      va = sb[PAD(elemA)]; vb = sb[PAD(elemB)];
      bool desc = ((elemA & S) == 0);   // elemB has same bit for S >= 256
      unsigned long long mx = (va > vb) ? va : vb;
      unsigned long long mn = (va > vb) ? vb : va;
      va = desc ? mx : mn; vb = desc ? mn : mx;
      for (int st = 32; st >= 1; st >>= 1){
        va = bstep(va, elemA, S, st);
        vb = bstep(vb, elemB, S, st);
      }
    }
  }
  // emit straight from registers: element index == descending rank
  const float4* pr = (const float4*)(prop + (size_t)img*ATOT*4);
  size_t base = (size_t)img*KTOT + c_CBASE[lvl];
  if (active){
    if (elemA < k){
      cand[base + elemA] = va;
      unsigned gidx = 0xFFFFFFFFu - (unsigned)(va & 0xFFFFFFFFull);
      float4 p = pr[gidx];
      cbox[base + elemA] = make_float4(fminf(fmaxf(p.x,0.f),512.f), fminf(fmaxf(p.y,0.f),512.f),
                                       fminf(fmaxf(p.z,0.f),512.f), fminf(fmaxf(p.w,0.f),512.f));
    }
    if (elemB < k){
      cand[base + elemB] = vb;
      unsigned gidx = 0xFFFFFFFFu - (unsigned)(vb & 0xFFFFFFFFull);
      float4 p = pr[gidx];
      cbox[base + elemB] = make_float4(fminf(fmaxf(p.x,0.f),512.f), fminf(fmaxf(p.y,0.f),512.f),
                                       fminf(fmaxf(p.z,0.f),512.f), fminf(fmaxf(p.w,0.f),512.f));
    }
  }
}

// ---------------- K2: IoU tiles -> edge lists (R25 packed form, validated) ----------------
extern "C" __global__ void __launch_bounds__(256)
k_mask(const float4* __restrict__ cbox, unsigned* __restrict__ ecnt,
       unsigned* __restrict__ eseg){
  __shared__ float4 pairXY[4][32];
  __shared__ float4 pairZW[4][32];
  int tid = threadIdx.x, lane = tid & 63, wv = tid >> 6;
  int bid = blockIdx.x;
  int tile = bid*4 + wv;                 // NTILES = 13344 = 3336*4, no remainder
  int img = tile / TILES_PER_IMG, r = tile % TILES_PER_IMG;
  int lvl = 0;
  while (r >= c_TILEPFX[lvl + 1]) ++lvl;
  int t = r - c_TILEPFX[lvl];
  int G = c_GLVL[lvl], k = c_KSEL[lvl];
  int gi = 0;
  while (t >= G - gi){ t -= G - gi; ++gi; }
  int gj = gi + t;
  int task = img*5 + lvl;
  const float4* cb = cbox + (size_t)img*KTOT + c_CBASE[lvl];

  int jj = gj*64 + lane;
  float4 bb = (jj < k) ? cb[jj] : make_float4(0.f,0.f,0.f,0.f);
  // partner box via shfl_xor(1); even lane writes XY quad, odd writes ZW quad
  float px_ = __shfl_xor(bb.x, 1), py_ = __shfl_xor(bb.y, 1);
  float pz_ = __shfl_xor(bb.z, 1), pw_ = __shfl_xor(bb.w, 1);
  int m2 = lane >> 1;
  if ((lane & 1) == 0)
    pairXY[wv][m2] = make_float4(bb.x, px_, bb.y, py_);   // {x_e, x_o, y_e, y_o}
  else
    pairZW[wv][m2] = make_float4(pz_, bb.z, pw_, bb.w);   // {z_e, z_o, w_e, w_o}
  WAVE_SYNC();   // own wave's ds_writes retired; no cross-wave state => no barrier

  int i = gi*64 + lane;
  float4 a = cb[(i < k) ? i : (k - 1)];  // clamped row; masked after the loop
  float aarea = (a.z - a.x) * (a.w - a.y);
  v2f az = {a.z, a.z}, ax = {a.x, a.x}, aw = {a.w, a.w}, ay = {a.y, a.y};
  v2f aA = {aarea, aarea};
  const float4* pxy = pairXY[wv];
  const float4* pzw = pairZW[wv];
  unsigned long long word = 0ull;
  #pragma unroll
  for (int jp = 0; jp < 32; ++jp){
    float4 q1 = pxy[jp];                 // wave-uniform ds_read_b128
    float4 q2 = pzw[jp];                 // wave-uniform ds_read_b128
    v2f bx = {q1.x, q1.y}, by = {q1.z, q1.w};
    v2f bz = {q2.x, q2.y}, bw = {q2.z, q2.w};
    v2f ix = vmin2(az, bz) - vmax2(ax, bx);
    v2f iy = vmin2(aw, bw) - vmax2(ay, by);
    v2f inter = ix * iy;
    v2f bA = (bz - bx) * (bw - by);
    v2f uni = (aA + bA) - inter;
    v2f p7 = uni * 0.7f;
    int d0 = __float_as_int(inter.x) - __float_as_int(p7.x);
    int d1 = __float_as_int(inter.y) - __float_as_int(p7.y);
    bool ov0 = (ix.x > 0.f) & (iy.x > 0.f);
    bool ov1 = (ix.y > 0.f) & (iy.y > 0.f);
    bool hit0 = ov0 & (d0 > 8);
    bool hit1 = ov1 & (d1 > 8);
    bool amb0 = ov0 & ((unsigned)(d0 + 8) <= 16u);   // == (d0>-9)&(d0<=8)
    bool amb1 = ov1 & ((unsigned)(d1 + 8) <= 16u);
    if (__any(amb0 | amb1)){             // wave-uniform s_cbranch; ~never taken
      if (amb0 && ((double)inter.x >= M_TIE * (double)uni.x)) hit0 = true;
      if (amb1 && ((double)inter.y >= M_TIE * (double)uni.y)) hit1 = true;
    }
    word |= (hit0 ? (1ull << (2*jp)) : 0ull) | (hit1 ? (1ull << (2*jp + 1)) : 0ull);
  }
  if (i >= k) word = 0ull;
  if (gi == gj)
    word &= (lane == 63) ? 0ull : (~0ull << (lane + 1));

  int nb = __popcll(word);
  int pfx = nb;
  for (int d = 1; d < 64; d <<= 1){
    int v = __shfl_up(pfx, d);
    if (lane >= d) pfx += v;
  }
  int total = __shfl(pfx, 63);
  if (total > 0){
    unsigned base = 0;
    if (lane == 0) base = atomicAdd(&ecnt[task*32 + gi], (unsigned)total);
    base = __shfl(base, 0);
    unsigned idx = base + (unsigned)(pfx - nb);
    unsigned* ep = eseg + (size_t)(task*32 + gi)*ESEG;
    while (word){
      int j = __ffsll(word) - 1; word &= word - 1;
      if (idx < ESEG) ep[idx] = ((unsigned)i << 16) | (unsigned)(gj*64 + j);
      ++idx;
    }
  }
}

// ---------------- K3: NMS word-sweep (R22 form, validated) ----------------
extern "C" __global__ void __launch_bounds__(1024)
k_scan(const unsigned long long* __restrict__ cand, const unsigned* __restrict__ ecnt,
       const unsigned* __restrict__ eseg, unsigned long long* __restrict__ clist,
       unsigned* __restrict__ ccnt){
  __shared__ unsigned ledge[6144];          // 24 KB edge cache
  __shared__ unsigned soff[33], wpfx[33];
  __shared__ unsigned long long smA[32][64]; // all words' suppression rows (16 KB)
  __shared__ unsigned long long hasIw[32];
  __shared__ unsigned long long remW[32], keepW[32];
  int task = blockIdx.x, img = task / 5, lvl = task % 5;
  int k = c_KSEL[lvl], nW = c_GLVL[lvl], tid = threadIdx.x;
  int lane = tid & 63, wv = tid >> 6;

  // parallel header: concurrent ecnt loads + wave prefix scan (lanes 0..31)
  if (tid < 32){
    unsigned e = (tid < nW) ? min(ecnt[task*32 + tid], (unsigned)ESEG) : 0u;
    unsigned pfx = e;
    #pragma unroll
    for (int d2 = 1; d2 < 32; d2 <<= 1){
      unsigned v = __shfl_up(pfx, d2);
      if (tid >= d2) pfx += v;
    }
    soff[tid] = pfx - e;          // exclusive prefix; lane nW (e=0) writes total
    if (tid == 31) soff[32] = pfx;
    remW[tid] = 0ull; hasIw[tid] = 0ull;
  }
  for (int i = tid; i < 32*64; i += 1024) ((unsigned long long*)smA)[i] = 0ull;
  __syncthreads();
  // wave-parallel staging + build: wave v handles segments v, v+16
  for (int w = wv; w < nW; w += 16){
    unsigned c = soff[w+1] - soff[w];
    const unsigned* ep = eseg + (size_t)(task*32 + w)*ESEG;
    for (unsigned e = lane; e < c; e += 64){
      unsigned p = soff[w] + e;
      unsigned ed = ep[e];
      if (p < 6144u) ledge[p] = ed;
      int i = (int)(ed >> 16), j = (int)(ed & 0xFFFFu);
      if ((j >> 6) == w){                  // intra-word edge of word w
        atomicOr(&smA[w][i & 63], 1ull << (j & 63));
        atomicOr(&hasIw[w], 1ull << (i & 63));
      }
    }
  }
  __syncthreads();

  if (tid < 64){     // wave 0: short serial greedy sweep over words
    for (int w = 0; w < nW; ++w){
      unsigned long long smreg = smA[w][lane];  // lane holds row `lane` of word w
      unsigned long long r = remW[w];           // includes propagations from words < w
      unsigned long long x = hasIw[w] & ~r;
      WAVE_SYNC();                              // smreg valid before readlane
      while (x){
        int i = __ffsll(x) - 1;
        unsigned rlo = __builtin_amdgcn_readlane((unsigned)smreg, i);
        unsigned rhi = __builtin_amdgcn_readlane((unsigned)(smreg >> 32), i);
        unsigned long long row = ((unsigned long long)rhi << 32) | rlo;
        r |= row;
        x &= ~(1ull << i);
        x &= ~r;
      }
      if (lane == 0) remW[w] = r;
      unsigned long long keep_w = ~r;           // all lanes computed r identically
      // propagate to later words using segment-w edges
      unsigned c = soff[w+1] - soff[w];
      if (c){
        const unsigned* ep = eseg + (size_t)(task*32 + w)*ESEG;
        for (unsigned e = lane; e < c; e += 64){
          unsigned p = soff[w] + e;
          unsigned ed = (p < 6144u) ? ledge[p] : ep[e];
          int i = (int)(ed >> 16), j = (int)(ed & 0xFFFFu), wj = j >> 6;
          if (wj != w && ((keep_w >> (i & 63)) & 1ull))
            atomicOr(&remW[wj], 1ull << (j & 63));
        }
      }
      WAVE_SYNC();                              // propagations visible next word
    }
    if (lane < 32){
      unsigned long long v = 0ull;
      if (lane < nW){
        int rem = k - lane*64;
        v = (rem >= 64) ? ~0ull : ((1ull << rem) - 1ull);
      }
      keepW[lane] = v & ~remW[lane];
    }
    WAVE_SYNC();
    if (lane == 0){
      unsigned s = 0;
      for (int w = 0; w < nW; ++w){ wpfx[w] = s; s += (unsigned)__popcll(keepW[w]); }
      ccnt[task] = s;
    }
  }
  __syncthreads();
  // compact kept candidates (preserves sorted order)
  size_t base = (size_t)img*KTOT + c_CBASE[lvl];
  for (int i = tid; i < k; i += 1024){
    unsigned long long w = keepW[i >> 6];
    if ((w >> (i & 63)) & 1ull){
      unsigned long long lowmask = (i & 63) ? ((1ull << (i & 63)) - 1ull) : 0ull;
      unsigned rank = wpfx[i >> 6] + (unsigned)__popcll(w & lowmask);
      clist[base + rank] = cand[base + i];
    }
  }
}

// ---------------- K4: 5-way rank merge (no sort), 8 blocks/image ----------------
__device__ __forceinline__ int cntGreater(const unsigned long long* base, int len,
                                          unsigned long long x){
  int lo = 0, hi = len;          // descending array, unique keys
  while (lo < hi){
    int mid = (lo + hi) >> 1;
    if (base[mid] > x) lo = mid + 1; else hi = mid;
  }
  return lo;
}

extern "C" __global__ void __launch_bounds__(1024)
k_merge(const float* __restrict__ prop, const float* __restrict__ obj,
        const unsigned long long* __restrict__ clist, const unsigned* __restrict__ ccnt,
        float* __restrict__ out){
  __shared__ unsigned long long keys[KTOT];   // ~54.4 KB
  __shared__ int loff[6], lcnt[5];
  int img = blockIdx.x >> 3, eighth = blockIdx.x & 7, tid = threadIdx.x;
  int lane = tid & 63, wv = tid >> 6;
  // parallel ccnt reads (R22)
  if (tid < 5) lcnt[tid] = (int)ccnt[img*5 + tid];
  __syncthreads();
  if (tid == 0){
    int s = 0;
    for (int l = 0; l < 5; ++l){ loff[l] = s; s += lcnt[l]; }
    loff[5] = s;
  }
  __syncthreads();
  // R23: wave-parallel staging — waves 0..14 split the 5 levels (3 waves each),
  // all levels' global reads in flight at once (disjoint writes, same values).
  if (wv < 15){
    int l = wv % 5, sub = wv / 5;
    size_t gb = (size_t)img*KTOT + c_CBASE[l];
    int c = lcnt[l], lo = loff[l];
    for (int e = sub*64 + lane; e < c; e += 192) keys[lo + e] = clist[gb + e];
  }
  __syncthreads();
  const float4* pr = (const float4*)(prop + (size_t)img*ATOT*4);
  const float*  o  = obj + (size_t)img*ATOT;
  float* ob = out + (size_t)img*POST*4;
  float* os = out + (size_t)NIMG*POST*4 + (size_t)img*POST;
  int tot = loff[5];
  for (int tt = tid; ; tt += 1024){
    int t = 8*tt + eighth;
    if (t >= tot) break;
    int lvl = 0;
    while (t >= loff[lvl + 1]) ++lvl;
    unsigned long long x = keys[t];
    int pos = t - loff[lvl];
    for (int l = 0; l < 5; ++l){
      if (l == lvl) continue;
      pos += cntGreater(keys + loff[l], lcnt[l], x);
    }
    if (pos < POST){
      unsigned gidx = 0xFFFFFFFFu - (unsigned)(x & 0xFFFFFFFFull);
      float4 p = pr[gidx];
      ob[pos*4 + 0] = fminf(fmaxf(p.x, 0.f), 512.f);
      ob[pos*4 + 1] = fminf(fmaxf(p.y, 0.f), 512.f);
      ob[pos*4 + 2] = fminf(fmaxf(p.z, 0.f), 512.f);
      ob[pos*4 + 3] = fminf(fmaxf(p.w, 0.f), 512.f);
      double sgm = 1.0 / (1.0 + exp(-(double)o[gidx]));  // correctly-rounded f32 sigmoid
      os[pos] = (float)sgm;
    }
  }
}

// ---------------- launch ----------------
extern "C" void kernel_launch(void* const* d_in, const int* in_sizes, int n_in,
                              void* d_out, int out_size, void* d_ws, size_t ws_size,
                              hipStream_t stream){
  const float* prop = (const float*)d_in[0];
  const float* obj  = (const float*)d_in[1];
  char* ws = (char*)d_ws;
  // ws layout (bytes):
  unsigned*           ecnt = (unsigned*)(ws);                        // 40*32*4 = 5120
  unsigned*           ccnt = (unsigned*)(ws + 5120);                 // 160 -> 5280 (pad 5632)
  unsigned long long* cand = (unsigned long long*)(ws + 5632);       // 445440 -> 451072
  unsigned long long* clist= (unsigned long long*)(ws + 451072);     // 445440 -> 896512
  float4*             cbox = (float4*)(ws + 896512);                 // 890880 -> 1787392
  unsigned*           eseg = (unsigned*)(ws + 1787392);              // 5242880 -> 7030272

  int out_n4 = out_size / 4;   // 80000 floats = 20000 float4
  hipLaunchKernelGGL(k_select, dim3(40),  dim3(1024), 0, stream, prop, obj, cand, cbox,
                     ecnt, (float4*)d_out, out_n4);
  hipLaunchKernelGGL(k_mask,   dim3(NTILES/4), dim3(256), 0, stream, cbox, ecnt, eseg);
  hipLaunchKernelGGL(k_scan,   dim3(40),  dim3(1024), 0, stream, cand, ecnt, eseg, clist, ccnt);
  hipLaunchKernelGGL(k_merge,  dim3(64),  dim3(1024), 0, stream, prop, obj, clist, ccnt, (float*)d_out);
}